// Round 5
// baseline (153.100 us; speedup 1.0000x reference)
//
#include <hip/hip_runtime.h>

#define T_TOTAL 200000
#define NL 49
#define NP 50
#define NB 20
#define THREADS 256
#define WPB (THREADS / 64)                      // waves per block = 4
#define CHUNK 64                                // timesteps per wave
#define NWAVES ((T_TOTAL + CHUNK - 1) / CHUNK)  // 3125
#define NBLOCKS ((NWAVES + WPB - 1) / WPB)      // 782

// Wave-per-timestep: lane b = skeleton node b (0..49). Tree accumulation done
// entirely in registers via 3-step pointer-jumping shuffle prefix (depth<=5).
// No LDS in the main loop, no barriers, no bank conflicts.
__global__ __launch_bounds__(THREADS, 8) void bbf_fused(
    const float* __restrict__ lines,
    const float* __restrict__ rootsx,
    const float* __restrict__ rootsy,
    const float* __restrict__ rootsz,
    const float* __restrict__ ax,
    const float* __restrict__ ay,
    const float* __restrict__ az,
    const float* __restrict__ tarx,
    const float* __restrict__ tary,
    const float* __restrict__ w,
    float* __restrict__ outx,
    float* __restrict__ outy,
    float* __restrict__ outz,
    double* __restrict__ partials)   // [NBLOCKS][2]
{
    __shared__ double redL[WPB], redR[WPB];

    const int tid  = threadIdx.x;
    const int lane = tid & 63;
    const int wv   = tid >> 6;
    const int gw   = blockIdx.x * WPB + wv;
    const int t_begin = gw * CHUNK;
    const int t_end   = min(t_begin + CHUNK, T_TOTAL);

    const bool isNode = (lane < NP);             // nodes 0..49
    const bool isLimb = (lane >= 1 && lane < NP);// limb index = lane-1

    // per-lane constant: bone length for the limb entering node `lane`
    float Lv = 0.f;
    if (isLimb) Lv = expf(lines[(lane - 1) % NB]);

    // static ancestor jump tables for node = lane (root-clamped at 0)
    const int a1 = isLimb ? ((lane - 1) >> 1) : 0;          // 1st ancestor
    const int a2 = (a1 > 0) ? ((a1 - 1) >> 1) : 0;          // 2nd ancestor
    const int a3 = (a2 > 0) ? ((a2 - 1) >> 1) : 0;          // 3rd
    const int a4 = (a3 > 0) ? ((a3 - 1) >> 1) : 0;          // 4th ancestor

    float lossAcc = 0.f, regAcc = 0.f;

    if (t_begin < T_TOTAL) {
        float pX = 0.f, pY = 0.f, pZ = 0.f;
        const int t_stop = (t_end < T_TOTAL) ? t_end + 1 : t_end;  // +1 halo
        for (int t = t_begin; t < t_stop; ++t) {
            // lane's own delta (limb lane-1), coalesced 49-lane load
            float dxv = 0.f, dyv = 0.f, dzv = 0.f;
            if (isLimb) {
                const size_t gi = (size_t)t * NL + (lane - 1);
                const float x = ax[gi], y = ay[gi], z = az[gi];
                const float nrm = sqrtf(x * x + y * y + z * z) + 1e-10f;
                const float s = Lv / nrm;
                dxv = x * s; dyv = y * s; dzv = z * s;
            }
            // pointer-jumping prefix: after steps {a1,a2,a4} lane b holds the
            // sum of deltas along its full root path (val at root stays 0)
            dxv += __shfl(dxv, a1); dyv += __shfl(dyv, a1); dzv += __shfl(dzv, a1);
            dxv += __shfl(dxv, a2); dyv += __shfl(dyv, a2); dzv += __shfl(dzv, a2);
            dxv += __shfl(dxv, a4); dyv += __shfl(dyv, a4); dzv += __shfl(dzv, a4);

            const float X = dxv + rootsx[t];   // wave-uniform root load
            const float Y = dyv + rootsy[t];
            const float Z = dzv + rootsz[t];

            if (t < t_end && isNode) {
                const size_t go = (size_t)t * NP + lane;
                outx[go] = X; outy[go] = Y; outz[go] = Z;
                const float dx = X - tarx[go];
                const float dy = Y - tary[go];
                lossAcc += w[go] * (dx * dx + dy * dy);
            }
            if (t > t_begin && isNode) {       // pair (t-1, t), owned iff t<=t_end
                const float ddx = pX - X;
                const float ddy = pY - Y;
                const float ddz = pZ - Z;
                regAcc += ddx * ddx + ddy * ddy + ddz * ddz;
            }
            pX = X; pY = Y; pZ = Z;
        }
    }

    // wave reduce -> cross-wave LDS -> per-block partial
    for (int off = 32; off > 0; off >>= 1) {
        lossAcc += __shfl_down(lossAcc, off);
        regAcc  += __shfl_down(regAcc, off);
    }
    if (lane == 0) { redL[wv] = (double)lossAcc; redR[wv] = (double)regAcc; }
    __syncthreads();
    if (tid == 0) {
        double l = 0.0, r = 0.0;
        for (int i = 0; i < WPB; ++i) { l += redL[i]; r += redR[i]; }
        partials[2 * (size_t)blockIdx.x]     = l;
        partials[2 * (size_t)blockIdx.x + 1] = r;
    }
}

__global__ __launch_bounds__(256) void bbf_finalize(
    const float* __restrict__ lines,
    const double* __restrict__ partials,
    float* __restrict__ out_total)
{
    __shared__ double rl[4], rr[4];
    const int tid = threadIdx.x;
    double l = 0.0, r = 0.0;
    for (int i = tid; i < NBLOCKS; i += 256) {
        l += partials[2 * (size_t)i];
        r += partials[2 * (size_t)i + 1];
    }
    for (int off = 32; off > 0; off >>= 1) {
        l += __shfl_down(l, off);
        r += __shfl_down(r, off);
    }
    const int wid = tid >> 6;
    if ((tid & 63) == 0) { rl[wid] = l; rr[wid] = r; }
    __syncthreads();
    if (tid == 0) {
        double L = 0.0, R = 0.0;
        for (int i = 0; i < 4; ++i) { L += rl[i]; R += rr[i]; }
        double reg1 = 0.0;
        for (int i = 0; i < NB; ++i) reg1 += (double)expf(lines[i]);
        const double loss = L / ((double)T_TOTAL * (double)NP);
        const double reg2 = R / ((double)(T_TOTAL - 1) * (double)NP);
        *out_total = (float)(loss + 0.001 * reg1 + 0.1 * reg2);
    }
}

extern "C" void kernel_launch(void* const* d_in, const int* in_sizes, int n_in,
                              void* d_out, int out_size, void* d_ws, size_t ws_size,
                              hipStream_t stream) {
    const float* lines  = (const float*)d_in[0];
    const float* rootsx = (const float*)d_in[1];
    const float* rootsy = (const float*)d_in[2];
    const float* rootsz = (const float*)d_in[3];
    const float* ax     = (const float*)d_in[4];
    const float* ay     = (const float*)d_in[5];
    const float* az     = (const float*)d_in[6];
    const float* tarx   = (const float*)d_in[7];
    const float* tary   = (const float*)d_in[8];
    const float* w      = (const float*)d_in[9];

    float* out = (float*)d_out;
    const size_t plane = (size_t)T_TOTAL * NP;
    float* outx = out;
    float* outy = out + plane;
    float* outz = out + 2 * plane;
    float* out_total = out + 3 * plane;

    double* partials = (double*)d_ws;   // NBLOCKS*2 doubles = 12.5 KB

    bbf_fused<<<NBLOCKS, THREADS, 0, stream>>>(
        lines, rootsx, rootsy, rootsz, ax, ay, az, tarx, tary, w,
        outx, outy, outz, partials);
    bbf_finalize<<<1, 256, 0, stream>>>(lines, partials, out_total);
}

// Round 6
// 106.530 us; speedup vs baseline: 1.4372x; 1.4372x over previous
//
#include <hip/hip_runtime.h>

#define T_TOTAL 200000
#define NL 49
#define NP 50
#define NB 20
#define THREADS 256
#define WPB (THREADS / 64)                      // waves per block = 4
#define CHUNK 16                                // timesteps per wave (grid-sizing: 12500 waves)
#define NWAVES (T_TOTAL / CHUNK)                // 12500 (exact)
#define NBLOCKS ((NWAVES + WPB - 1) / WPB)      // 3125 -> ~12 blocks/CU of work

// Wave-per-timestep: lane b = skeleton node b (0..49). Tree accumulation done
// entirely in registers via 3-step pointer-jumping shuffle prefix (depth<=5).
// No LDS in the main loop, no barriers, no bank conflicts.
// CHUNK=16 sizes the grid so 8 blocks/CU stay resident (32 waves = occupancy cap).
__global__ __launch_bounds__(THREADS, 8) void bbf_fused(
    const float* __restrict__ lines,
    const float* __restrict__ rootsx,
    const float* __restrict__ rootsy,
    const float* __restrict__ rootsz,
    const float* __restrict__ ax,
    const float* __restrict__ ay,
    const float* __restrict__ az,
    const float* __restrict__ tarx,
    const float* __restrict__ tary,
    const float* __restrict__ w,
    float* __restrict__ outx,
    float* __restrict__ outy,
    float* __restrict__ outz,
    double* __restrict__ partials)   // [NBLOCKS][2]
{
    __shared__ double redL[WPB], redR[WPB];

    const int tid  = threadIdx.x;
    const int lane = tid & 63;
    const int wv   = tid >> 6;
    const int gw   = blockIdx.x * WPB + wv;
    const int t_begin = gw * CHUNK;
    const int t_end   = t_begin + CHUNK;         // exact division, always <= T_TOTAL

    const bool isNode = (lane < NP);             // nodes 0..49
    const bool isLimb = (lane >= 1 && lane < NP);// limb index = lane-1

    // per-lane constant: bone length for the limb entering node `lane`
    float Lv = 0.f;
    if (isLimb) Lv = expf(lines[(lane - 1) % NB]);

    // static ancestor jump tables for node = lane (root-clamped at 0)
    const int a1 = isLimb ? ((lane - 1) >> 1) : 0;          // 1st ancestor
    const int a2 = (a1 > 0) ? ((a1 - 1) >> 1) : 0;          // 2nd ancestor
    const int a3 = (a2 > 0) ? ((a2 - 1) >> 1) : 0;          // 3rd
    const int a4 = (a3 > 0) ? ((a3 - 1) >> 1) : 0;          // 4th ancestor

    float lossAcc = 0.f, regAcc = 0.f;

    {
        float pX = 0.f, pY = 0.f, pZ = 0.f;
        const int t_stop = (t_end < T_TOTAL) ? t_end + 1 : t_end;  // +1 halo
        for (int t = t_begin; t < t_stop; ++t) {
            // lane's own delta (limb lane-1), coalesced 49-lane load
            float dxv = 0.f, dyv = 0.f, dzv = 0.f;
            if (isLimb) {
                const size_t gi = (size_t)t * NL + (lane - 1);
                const float x = ax[gi], y = ay[gi], z = az[gi];
                const float nrm = sqrtf(x * x + y * y + z * z) + 1e-10f;
                const float s = Lv / nrm;
                dxv = x * s; dyv = y * s; dzv = z * s;
            }
            // pointer-jumping prefix: after steps {a1,a2,a4} lane b holds the
            // sum of deltas along its full root path (val at root stays 0)
            dxv += __shfl(dxv, a1); dyv += __shfl(dyv, a1); dzv += __shfl(dzv, a1);
            dxv += __shfl(dxv, a2); dyv += __shfl(dyv, a2); dzv += __shfl(dzv, a2);
            dxv += __shfl(dxv, a4); dyv += __shfl(dyv, a4); dzv += __shfl(dzv, a4);

            const float X = dxv + rootsx[t];   // wave-uniform root load (s_load)
            const float Y = dyv + rootsy[t];
            const float Z = dzv + rootsz[t];

            if (t < t_end && isNode) {
                const size_t go = (size_t)t * NP + lane;
                outx[go] = X; outy[go] = Y; outz[go] = Z;
                const float dx = X - tarx[go];
                const float dy = Y - tary[go];
                lossAcc += w[go] * (dx * dx + dy * dy);
            }
            if (t > t_begin && isNode) {       // pair (t-1, t), owned iff t<=t_end
                const float ddx = pX - X;
                const float ddy = pY - Y;
                const float ddz = pZ - Z;
                regAcc += ddx * ddx + ddy * ddy + ddz * ddz;
            }
            pX = X; pY = Y; pZ = Z;
        }
    }

    // wave reduce -> cross-wave LDS -> per-block partial
    for (int off = 32; off > 0; off >>= 1) {
        lossAcc += __shfl_down(lossAcc, off);
        regAcc  += __shfl_down(regAcc, off);
    }
    if (lane == 0) { redL[wv] = (double)lossAcc; redR[wv] = (double)regAcc; }
    __syncthreads();
    if (tid == 0) {
        double l = 0.0, r = 0.0;
        for (int i = 0; i < WPB; ++i) { l += redL[i]; r += redR[i]; }
        partials[2 * (size_t)blockIdx.x]     = l;
        partials[2 * (size_t)blockIdx.x + 1] = r;
    }
}

__global__ __launch_bounds__(256) void bbf_finalize(
    const float* __restrict__ lines,
    const double* __restrict__ partials,
    float* __restrict__ out_total)
{
    __shared__ double rl[4], rr[4];
    const int tid = threadIdx.x;
    double l = 0.0, r = 0.0;
    for (int i = tid; i < NBLOCKS; i += 256) {
        l += partials[2 * (size_t)i];
        r += partials[2 * (size_t)i + 1];
    }
    for (int off = 32; off > 0; off >>= 1) {
        l += __shfl_down(l, off);
        r += __shfl_down(r, off);
    }
    const int wid = tid >> 6;
    if ((tid & 63) == 0) { rl[wid] = l; rr[wid] = r; }
    __syncthreads();
    if (tid == 0) {
        double L = 0.0, R = 0.0;
        for (int i = 0; i < 4; ++i) { L += rl[i]; R += rr[i]; }
        double reg1 = 0.0;
        for (int i = 0; i < NB; ++i) reg1 += (double)expf(lines[i]);
        const double loss = L / ((double)T_TOTAL * (double)NP);
        const double reg2 = R / ((double)(T_TOTAL - 1) * (double)NP);
        *out_total = (float)(loss + 0.001 * reg1 + 0.1 * reg2);
    }
}

extern "C" void kernel_launch(void* const* d_in, const int* in_sizes, int n_in,
                              void* d_out, int out_size, void* d_ws, size_t ws_size,
                              hipStream_t stream) {
    const float* lines  = (const float*)d_in[0];
    const float* rootsx = (const float*)d_in[1];
    const float* rootsy = (const float*)d_in[2];
    const float* rootsz = (const float*)d_in[3];
    const float* ax     = (const float*)d_in[4];
    const float* ay     = (const float*)d_in[5];
    const float* az     = (const float*)d_in[6];
    const float* tarx   = (const float*)d_in[7];
    const float* tary   = (const float*)d_in[8];
    const float* w      = (const float*)d_in[9];

    float* out = (float*)d_out;
    const size_t plane = (size_t)T_TOTAL * NP;
    float* outx = out;
    float* outy = out + plane;
    float* outz = out + 2 * plane;
    float* out_total = out + 3 * plane;

    double* partials = (double*)d_ws;   // NBLOCKS*2 doubles = 50 KB

    bbf_fused<<<NBLOCKS, THREADS, 0, stream>>>(
        lines, rootsx, rootsy, rootsz, ax, ay, az, tarx, tary, w,
        outx, outy, outz, partials);
    bbf_finalize<<<1, 256, 0, stream>>>(lines, partials, out_total);
}